// Round 1
// baseline (1305.843 us; speedup 1.0000x reference)
//
#include <hip/hip_runtime.h>

#define N_NODES 100000
#define DIM     128
#define GROWS   64

__device__ __forceinline__ void atomAddF(float* p, float v) {
    unsafeAtomicAdd(p, v);  // native global_atomic_add_f32 on gfx950
}

// ---------------------------------------------------------------------------
// Kernel 1: edge scatter — agg[dst] += x[src], cnt[dst] += 1
// 32 lanes per edge, each lane handles 4 channels (float4 gather, 4 atomics).
// ---------------------------------------------------------------------------
__global__ __launch_bounds__(256) void scatter_kernel(
    const float* __restrict__ x, const int* __restrict__ ei,
    float* __restrict__ agg, float* __restrict__ cnt, int E)
{
    int g = blockIdx.x * 256 + threadIdx.x;
    int e = g >> 5;
    if (e >= E) return;
    int lane = threadIdx.x & 31;
    int src = ei[e];          // edge_index[0][e]
    int dst = ei[E + e];      // edge_index[1][e]
    const float4 v = *reinterpret_cast<const float4*>(x + (size_t)src * DIM + lane * 4);
    float* a = agg + (size_t)dst * DIM + lane * 4;
    atomAddF(a + 0, v.x);
    atomAddF(a + 1, v.y);
    atomAddF(a + 2, v.z);
    atomAddF(a + 3, v.w);
    if (lane == 0) atomAddF(cnt + dst, 1.0f);
}

// ---------------------------------------------------------------------------
// Kernel 2: fused GEMM  out = (agg/cnt) @ Wl^T + bl + x @ Wr^T
// + per-channel sum / sumsq partials for BatchNorm (atomics into ws stats).
// Tile: 64 rows x 128 cols per 256-thread block; 8x4 accumulators/thread.
// K is traversed in 4 chunks of 64 (chunks 0,1 = mean_nb/Wl; 2,3 = x/Wr).
// ---------------------------------------------------------------------------
__global__ __launch_bounds__(256, 2) void fused_gemm_kernel(
    const float* __restrict__ x, const float* __restrict__ agg,
    const float* __restrict__ cnt,
    const float* __restrict__ Wl, const float* __restrict__ Wr,
    const float* __restrict__ bl,
    float* __restrict__ out, float* __restrict__ ssum, float* __restrict__ ssq)
{
    __shared__ float As[GROWS][64];   // 16 KB  (A chunk; reused as reduction buf)
    __shared__ float Wt[64][DIM];     // 32 KB  (W chunk, transposed: Wt[k][d])
    __shared__ float invs[GROWS];

    const int t  = threadIdx.x;
    const int tx = t & 31;            // channel group: d = tx*4 .. tx*4+3
    const int ty = t >> 5;            // row group:     n = row0 + ty*8 .. +7
    const int row0 = blockIdx.x * GROWS;

    if (t < GROWS) {
        int n = row0 + t;
        invs[t] = (n < N_NODES) ? 1.0f / fmaxf(cnt[n], 1.0f) : 0.0f;
    }

    float acc[8][4];
    #pragma unroll
    for (int r = 0; r < 8; ++r)
        #pragma unroll
        for (int c = 0; c < 4; ++c) acc[r][c] = 0.f;

    const int d_w  = t & 127;         // W-staging: d fast across lanes (conflict-free LDS writes)
    const int half = t >> 7;

    for (int kt = 0; kt < 4; ++kt) {
        const float* __restrict__ srcmat = (kt < 2) ? agg : x;
        const float* __restrict__ Wm     = (kt < 2) ? Wl  : Wr;
        const int kbase = (kt & 1) * 64;
        __syncthreads();
        // --- stage A chunk: 64 rows x 64 k ---
        #pragma unroll
        for (int j = 0; j < 4; ++j) {
            int l  = t + j * 256;          // 0..1023 float4 slots
            int r  = l >> 4;               // row 0..63
            int kk = (l & 15) << 2;        // k 0..60
            int n  = row0 + r;
            float4 v = make_float4(0.f, 0.f, 0.f, 0.f);
            if (n < N_NODES)
                v = *reinterpret_cast<const float4*>(srcmat + (size_t)n * DIM + kbase + kk);
            if (kt < 2) {                  // mean = agg * (1/max(cnt,1))
                float iv = invs[r];
                v.x *= iv; v.y *= iv; v.z *= iv; v.w *= iv;
            }
            *reinterpret_cast<float4*>(&As[r][kk]) = v;
        }
        // --- stage W chunk transposed: Wt[k][d] = Wm[d][kbase+k] ---
        #pragma unroll
        for (int j = 0; j < 8; ++j) {
            int k4 = (half * 8 + j) * 4;
            float4 w = *reinterpret_cast<const float4*>(Wm + d_w * DIM + kbase + k4);
            Wt[k4 + 0][d_w] = w.x;
            Wt[k4 + 1][d_w] = w.y;
            Wt[k4 + 2][d_w] = w.z;
            Wt[k4 + 3][d_w] = w.w;
        }
        __syncthreads();
        // --- FMA loop ---
        #pragma unroll 4
        for (int k = 0; k < 64; ++k) {
            float4 wv = *reinterpret_cast<const float4*>(&Wt[k][tx * 4]);
            #pragma unroll
            for (int r = 0; r < 8; ++r) {
                float a = As[ty * 8 + r][k];     // intra-wave broadcast (2 addrs/wave)
                acc[r][0] = fmaf(a, wv.x, acc[r][0]);
                acc[r][1] = fmaf(a, wv.y, acc[r][1]);
                acc[r][2] = fmaf(a, wv.z, acc[r][2]);
                acc[r][3] = fmaf(a, wv.w, acc[r][3]);
            }
        }
    }

    // --- bias + store pre-BN activations to d_out ---
    const float4 bv = *reinterpret_cast<const float4*>(bl + tx * 4);
    #pragma unroll
    for (int r = 0; r < 8; ++r) {
        acc[r][0] += bv.x; acc[r][1] += bv.y; acc[r][2] += bv.z; acc[r][3] += bv.w;
        int n = row0 + ty * 8 + r;
        if (n < N_NODES)
            *reinterpret_cast<float4*>(out + (size_t)n * DIM + tx * 4) =
                make_float4(acc[r][0], acc[r][1], acc[r][2], acc[r][3]);
    }

    // --- per-channel block stats (deterministic LDS reduction, reuse As) ---
    __syncthreads();                       // everyone done reading As
    float* red0 = &As[0][0];               // [8][128] partial sums
    float* red1 = &As[0][0] + 1024;        // [8][128] partial sumsqs
    #pragma unroll
    for (int c = 0; c < 4; ++c) {
        float s = 0.f, q = 0.f;
        #pragma unroll
        for (int r = 0; r < 8; ++r) {
            int n = row0 + ty * 8 + r;
            if (n < N_NODES) { float v = acc[r][c]; s += v; q = fmaf(v, v, q); }
        }
        red0[ty * DIM + tx * 4 + c] = s;
        red1[ty * DIM + tx * 4 + c] = q;
    }
    __syncthreads();
    if (t < DIM) {
        float s = 0.f, q = 0.f;
        #pragma unroll
        for (int j = 0; j < 8; ++j) {
            s += red0[j * DIM + t];
            q += red1[j * DIM + t];
        }
        atomAddF(&ssum[t], s);
        atomAddF(&ssq[t], q);
    }
}

// ---------------------------------------------------------------------------
// Kernel 3: finalize BN statistics (one block, 128 threads)
// ---------------------------------------------------------------------------
__global__ void stats_kernel(const float* __restrict__ ssum, const float* __restrict__ ssq,
                             float* __restrict__ mu, float* __restrict__ rs)
{
    int d = threadIdx.x;
    float m = ssum[d] * (1.0f / N_NODES);
    float v = ssq[d] * (1.0f / N_NODES) - m * m;   // biased variance
    mu[d] = m;
    rs[d] = rsqrtf(fmaxf(v, 0.f) + 1e-5f);
}

// ---------------------------------------------------------------------------
// Kernel 4: BN apply + ReLU + residual (in-place on d_out)
// ---------------------------------------------------------------------------
__global__ __launch_bounds__(256) void epilogue_kernel(
    float* __restrict__ out, const float* __restrict__ x,
    const float* __restrict__ gamma, const float* __restrict__ beta,
    const float* __restrict__ mu, const float* __restrict__ rs)
{
    size_t i   = (size_t)blockIdx.x * 256 + threadIdx.x;
    size_t idx = i * 4;
    if (idx >= (size_t)N_NODES * DIM) return;
    int c = (int)(idx & (DIM - 1));        // channel base (multiple of 4)
    float4 p  = *reinterpret_cast<const float4*>(out + idx);
    float4 xv = *reinterpret_cast<const float4*>(x + idx);
    float4 gv = *reinterpret_cast<const float4*>(gamma + c);
    float4 bv = *reinterpret_cast<const float4*>(beta + c);
    float4 mv = *reinterpret_cast<const float4*>(mu + c);
    float4 rv = *reinterpret_cast<const float4*>(rs + c);
    float4 o;
    o.x = fmaxf(fmaf(gv.x * (p.x - mv.x), rv.x, bv.x), 0.f) + xv.x;
    o.y = fmaxf(fmaf(gv.y * (p.y - mv.y), rv.y, bv.y), 0.f) + xv.y;
    o.z = fmaxf(fmaf(gv.z * (p.z - mv.z), rv.z, bv.z), 0.f) + xv.z;
    o.w = fmaxf(fmaf(gv.w * (p.w - mv.w), rv.w, bv.w), 0.f) + xv.w;
    *reinterpret_cast<float4*>(out + idx) = o;
}

// ---------------------------------------------------------------------------
extern "C" void kernel_launch(void* const* d_in, const int* in_sizes, int n_in,
                              void* d_out, int out_size, void* d_ws, size_t ws_size,
                              hipStream_t stream)
{
    const float* x     = (const float*)d_in[0];
    const int*   ei    = (const int*)  d_in[1];
    const float* Wl    = (const float*)d_in[2];
    const float* bl    = (const float*)d_in[3];
    const float* Wr    = (const float*)d_in[4];
    const float* gamma = (const float*)d_in[5];
    const float* beta  = (const float*)d_in[6];
    float* out = (float*)d_out;

    // ws layout (floats): agg[N*D] | cnt[N] | ssum[D] | ssq[D] | mu[D] | rs[D]
    float* ws   = (float*)d_ws;
    float* agg  = ws;
    float* cnt  = ws + (size_t)N_NODES * DIM;
    float* ssum = cnt + N_NODES;
    float* ssq  = ssum + DIM;
    float* mu   = ssq + DIM;
    float* rs   = mu + DIM;

    const int E = in_sizes[1] / 2;

    // zero agg + cnt + ssum + ssq (~51.6 MB)
    hipMemsetAsync(ws, 0, ((size_t)N_NODES * DIM + N_NODES + 2 * DIM) * sizeof(float), stream);

    scatter_kernel<<<(E * 32 + 255) / 256, 256, 0, stream>>>(x, ei, agg, cnt, E);

    fused_gemm_kernel<<<(N_NODES + GROWS - 1) / GROWS, 256, 0, stream>>>(
        x, agg, cnt, Wl, Wr, bl, out, ssum, ssq);

    stats_kernel<<<1, DIM, 0, stream>>>(ssum, ssq, mu, rs);

    epilogue_kernel<<<((size_t)N_NODES * DIM / 4 + 255) / 256, 256, 0, stream>>>(
        out, x, gamma, beta, mu, rs);
}

// Round 2
// 350.473 us; speedup vs baseline: 3.7259x; 3.7259x over previous
//
#include <hip/hip_runtime.h>

#define N_NODES 100000
#define DIM     128
#define GROWS   64
#define SCAN_B  1024                       // elements per scan block
#define NSCANB  ((N_NODES + SCAN_B - 1) / SCAN_B)   // 98

__device__ __forceinline__ void atomAddF(float* p, float v) {
    unsafeAtomicAdd(p, v);
}

// ---------------------------------------------------------------------------
// CSR build step 1: histogram of dst
// ---------------------------------------------------------------------------
__global__ __launch_bounds__(256) void hist_kernel(
    const int* __restrict__ ei, int* __restrict__ counts, int E)
{
    int e = blockIdx.x * 256 + threadIdx.x;
    if (e >= E) return;
    atomicAdd(&counts[ei[E + e]], 1);
}

// ---------------------------------------------------------------------------
// CSR build step 2a: per-block inclusive scan of counts
// ---------------------------------------------------------------------------
__global__ __launch_bounds__(SCAN_B) void scan_block_kernel(
    const int* __restrict__ counts, int* __restrict__ incl, int* __restrict__ blksum)
{
    __shared__ int sh[SCAN_B];
    int t = threadIdx.x;
    int i = blockIdx.x * SCAN_B + t;
    sh[t] = (i < N_NODES) ? counts[i] : 0;
    __syncthreads();
    #pragma unroll
    for (int ofs = 1; ofs < SCAN_B; ofs <<= 1) {
        int add = (t >= ofs) ? sh[t - ofs] : 0;
        __syncthreads();
        sh[t] += add;
        __syncthreads();
    }
    if (i < N_NODES) incl[i] = sh[t];
    if (t == SCAN_B - 1) blksum[blockIdx.x] = sh[t];
}

// ---------------------------------------------------------------------------
// CSR build step 2b: exclusive scan of the 98 block sums (1 block)
// ---------------------------------------------------------------------------
__global__ void scan_tops_kernel(const int* __restrict__ blksum, int* __restrict__ blkoff)
{
    if (threadIdx.x == 0) {
        int run = 0;
        for (int b = 0; b < NSCANB; ++b) { blkoff[b] = run; run += blksum[b]; }
    }
}

// ---------------------------------------------------------------------------
// CSR build step 2c: row_start[i] = exclusive prefix; wo = write cursors
// ---------------------------------------------------------------------------
__global__ __launch_bounds__(256) void scan_add_kernel(
    const int* __restrict__ counts, const int* __restrict__ incl,
    const int* __restrict__ blkoff,
    int* __restrict__ row_start, int* __restrict__ wo, int E)
{
    int i = blockIdx.x * 256 + threadIdx.x;
    if (i == 0) row_start[N_NODES] = E;
    if (i >= N_NODES) return;
    int excl = incl[i] + blkoff[i / SCAN_B] - counts[i];
    row_start[i] = excl;
    wo[i] = excl;
}

// ---------------------------------------------------------------------------
// CSR build step 3: bucket-fill sources sorted by dst
// ---------------------------------------------------------------------------
__global__ __launch_bounds__(256) void fill_kernel(
    const int* __restrict__ ei, int* __restrict__ wo, int* __restrict__ srcs, int E)
{
    int e = blockIdx.x * 256 + threadIdx.x;
    if (e >= E) return;
    int dst = ei[E + e];
    int pos = atomicAdd(&wo[dst], 1);
    srcs[pos] = ei[e];
}

// ---------------------------------------------------------------------------
// Aggregation: one 32-lane group per node; registers accumulate, write mean.
// No atomics, deterministic per node.
// ---------------------------------------------------------------------------
__global__ __launch_bounds__(256) void aggregate_kernel(
    const float* __restrict__ x, const int* __restrict__ srcs,
    const int* __restrict__ row_start, float* __restrict__ agg)
{
    int n = blockIdx.x * 8 + (threadIdx.x >> 5);
    if (n >= N_NODES) return;
    int lane = threadIdx.x & 31;
    int beg = row_start[n], end = row_start[n + 1];
    float4 acc = make_float4(0.f, 0.f, 0.f, 0.f);
    int e = beg;
    for (; e + 1 < end; e += 2) {              // 2-deep for ILP
        size_t s0 = (size_t)srcs[e]     * DIM + lane * 4;
        size_t s1 = (size_t)srcs[e + 1] * DIM + lane * 4;
        float4 v0 = *reinterpret_cast<const float4*>(x + s0);
        float4 v1 = *reinterpret_cast<const float4*>(x + s1);
        acc.x += v0.x + v1.x; acc.y += v0.y + v1.y;
        acc.z += v0.z + v1.z; acc.w += v0.w + v1.w;
    }
    if (e < end) {
        float4 v = *reinterpret_cast<const float4*>(x + (size_t)srcs[e] * DIM + lane * 4);
        acc.x += v.x; acc.y += v.y; acc.z += v.z; acc.w += v.w;
    }
    float inv = 1.0f / (float)max(end - beg, 1);
    acc.x *= inv; acc.y *= inv; acc.z *= inv; acc.w *= inv;
    *reinterpret_cast<float4*>(agg + (size_t)n * DIM + lane * 4) = acc;
}

// ---------------------------------------------------------------------------
// Fused GEMM  out = agg @ Wl^T + bl + x @ Wr^T   (agg already holds the mean)
// + per-channel sum/sumsq partials for BatchNorm.
// ---------------------------------------------------------------------------
__global__ __launch_bounds__(256, 2) void fused_gemm_kernel(
    const float* __restrict__ x, const float* __restrict__ agg,
    const float* __restrict__ Wl, const float* __restrict__ Wr,
    const float* __restrict__ bl,
    float* __restrict__ out, float* __restrict__ ssum, float* __restrict__ ssq)
{
    __shared__ float As[GROWS][64];   // 16 KB (A chunk; reused as reduction buf)
    __shared__ float Wt[64][DIM];     // 32 KB (W chunk transposed: Wt[k][d])

    const int t  = threadIdx.x;
    const int tx = t & 31;
    const int ty = t >> 5;
    const int row0 = blockIdx.x * GROWS;

    float acc[8][4];
    #pragma unroll
    for (int r = 0; r < 8; ++r)
        #pragma unroll
        for (int c = 0; c < 4; ++c) acc[r][c] = 0.f;

    const int d_w  = t & 127;
    const int half = t >> 7;

    for (int kt = 0; kt < 4; ++kt) {
        const float* __restrict__ srcmat = (kt < 2) ? agg : x;
        const float* __restrict__ Wm     = (kt < 2) ? Wl  : Wr;
        const int kbase = (kt & 1) * 64;
        __syncthreads();
        #pragma unroll
        for (int j = 0; j < 4; ++j) {
            int l  = t + j * 256;
            int r  = l >> 4;
            int kk = (l & 15) << 2;
            int n  = row0 + r;
            float4 v = make_float4(0.f, 0.f, 0.f, 0.f);
            if (n < N_NODES)
                v = *reinterpret_cast<const float4*>(srcmat + (size_t)n * DIM + kbase + kk);
            *reinterpret_cast<float4*>(&As[r][kk]) = v;
        }
        #pragma unroll
        for (int j = 0; j < 8; ++j) {
            int k4 = (half * 8 + j) * 4;
            float4 w = *reinterpret_cast<const float4*>(Wm + d_w * DIM + kbase + k4);
            Wt[k4 + 0][d_w] = w.x;
            Wt[k4 + 1][d_w] = w.y;
            Wt[k4 + 2][d_w] = w.z;
            Wt[k4 + 3][d_w] = w.w;
        }
        __syncthreads();
        #pragma unroll 4
        for (int k = 0; k < 64; ++k) {
            float4 wv = *reinterpret_cast<const float4*>(&Wt[k][tx * 4]);
            #pragma unroll
            for (int r = 0; r < 8; ++r) {
                float a = As[ty * 8 + r][k];
                acc[r][0] = fmaf(a, wv.x, acc[r][0]);
                acc[r][1] = fmaf(a, wv.y, acc[r][1]);
                acc[r][2] = fmaf(a, wv.z, acc[r][2]);
                acc[r][3] = fmaf(a, wv.w, acc[r][3]);
            }
        }
    }

    const float4 bv = *reinterpret_cast<const float4*>(bl + tx * 4);
    #pragma unroll
    for (int r = 0; r < 8; ++r) {
        acc[r][0] += bv.x; acc[r][1] += bv.y; acc[r][2] += bv.z; acc[r][3] += bv.w;
        int n = row0 + ty * 8 + r;
        if (n < N_NODES)
            *reinterpret_cast<float4*>(out + (size_t)n * DIM + tx * 4) =
                make_float4(acc[r][0], acc[r][1], acc[r][2], acc[r][3]);
    }

    __syncthreads();
    float* red0 = &As[0][0];
    float* red1 = &As[0][0] + 1024;
    #pragma unroll
    for (int c = 0; c < 4; ++c) {
        float s = 0.f, q = 0.f;
        #pragma unroll
        for (int r = 0; r < 8; ++r) {
            int n = row0 + ty * 8 + r;
            if (n < N_NODES) { float v = acc[r][c]; s += v; q = fmaf(v, v, q); }
        }
        red0[ty * DIM + tx * 4 + c] = s;
        red1[ty * DIM + tx * 4 + c] = q;
    }
    __syncthreads();
    if (t < DIM) {
        float s = 0.f, q = 0.f;
        #pragma unroll
        for (int j = 0; j < 8; ++j) {
            s += red0[j * DIM + t];
            q += red1[j * DIM + t];
        }
        atomAddF(&ssum[t], s);
        atomAddF(&ssq[t], q);
    }
}

// ---------------------------------------------------------------------------
__global__ void stats_kernel(const float* __restrict__ ssum, const float* __restrict__ ssq,
                             float* __restrict__ mu, float* __restrict__ rs)
{
    int d = threadIdx.x;
    float m = ssum[d] * (1.0f / N_NODES);
    float v = ssq[d] * (1.0f / N_NODES) - m * m;
    mu[d] = m;
    rs[d] = rsqrtf(fmaxf(v, 0.f) + 1e-5f);
}

// ---------------------------------------------------------------------------
__global__ __launch_bounds__(256) void epilogue_kernel(
    float* __restrict__ out, const float* __restrict__ x,
    const float* __restrict__ gamma, const float* __restrict__ beta,
    const float* __restrict__ mu, const float* __restrict__ rs)
{
    size_t i   = (size_t)blockIdx.x * 256 + threadIdx.x;
    size_t idx = i * 4;
    if (idx >= (size_t)N_NODES * DIM) return;
    int c = (int)(idx & (DIM - 1));
    float4 p  = *reinterpret_cast<const float4*>(out + idx);
    float4 xv = *reinterpret_cast<const float4*>(x + idx);
    float4 gv = *reinterpret_cast<const float4*>(gamma + c);
    float4 bv = *reinterpret_cast<const float4*>(beta + c);
    float4 mv = *reinterpret_cast<const float4*>(mu + c);
    float4 rv = *reinterpret_cast<const float4*>(rs + c);
    float4 o;
    o.x = fmaxf(fmaf(gv.x * (p.x - mv.x), rv.x, bv.x), 0.f) + xv.x;
    o.y = fmaxf(fmaf(gv.y * (p.y - mv.y), rv.y, bv.y), 0.f) + xv.y;
    o.z = fmaxf(fmaf(gv.z * (p.z - mv.z), rv.z, bv.z), 0.f) + xv.z;
    o.w = fmaxf(fmaf(gv.w * (p.w - mv.w), rv.w, bv.w), 0.f) + xv.w;
    *reinterpret_cast<float4*>(out + idx) = o;
}

// ---------------------------------------------------------------------------
extern "C" void kernel_launch(void* const* d_in, const int* in_sizes, int n_in,
                              void* d_out, int out_size, void* d_ws, size_t ws_size,
                              hipStream_t stream)
{
    const float* x     = (const float*)d_in[0];
    const int*   ei    = (const int*)  d_in[1];
    const float* Wl    = (const float*)d_in[2];
    const float* bl    = (const float*)d_in[3];
    const float* Wr    = (const float*)d_in[4];
    const float* gamma = (const float*)d_in[5];
    const float* beta  = (const float*)d_in[6];
    float* out = (float*)d_out;

    const int E = in_sizes[1] / 2;

    // ws layout:
    // agg[N*D] f32 | srcs[E] i32 | row_start[N+1] i32 | wo[N] i32 |
    // incl[N] i32 | blksum[128] i32 | blkoff[128] i32 |
    // counts[N] i32 | ssum[D] f | ssq[D] f | mu[D] f | rs[D] f
    char* w = (char*)d_ws;
    float* agg       = (float*)w;                  w += (size_t)N_NODES * DIM * 4;
    int*   srcs      = (int*)w;                    w += (size_t)E * 4;
    int*   row_start = (int*)w;                    w += (size_t)(N_NODES + 1) * 4;
    int*   wo        = (int*)w;                    w += (size_t)N_NODES * 4;
    int*   incl      = (int*)w;                    w += (size_t)N_NODES * 4;
    int*   blksum    = (int*)w;                    w += 128 * 4;
    int*   blkoff    = (int*)w;                    w += 128 * 4;
    int*   counts    = (int*)w;                    w += (size_t)N_NODES * 4;
    float* ssum      = (float*)w;                  w += DIM * 4;
    float* ssq       = (float*)w;                  w += DIM * 4;
    float* mu        = (float*)w;                  w += DIM * 4;
    float* rs        = (float*)w;                  /* end */

    // zero counts + ssum + ssq (contiguous: counts .. ssq)
    hipMemsetAsync(counts, 0, ((size_t)N_NODES + 2 * DIM) * 4, stream);

    hist_kernel<<<(E + 255) / 256, 256, 0, stream>>>(ei, counts, E);
    scan_block_kernel<<<NSCANB, SCAN_B, 0, stream>>>(counts, incl, blksum);
    scan_tops_kernel<<<1, 64, 0, stream>>>(blksum, blkoff);
    scan_add_kernel<<<(N_NODES + 255) / 256, 256, 0, stream>>>(
        counts, incl, blkoff, row_start, wo, E);
    fill_kernel<<<(E + 255) / 256, 256, 0, stream>>>(ei, wo, srcs, E);

    aggregate_kernel<<<(N_NODES + 7) / 8, 256, 0, stream>>>(x, srcs, row_start, agg);

    fused_gemm_kernel<<<(N_NODES + GROWS - 1) / GROWS, 256, 0, stream>>>(
        x, agg, Wl, Wr, bl, out, ssum, ssq);

    stats_kernel<<<1, DIM, 0, stream>>>(ssum, ssq, mu, rs);

    epilogue_kernel<<<((size_t)N_NODES * DIM / 4 + 255) / 256, 256, 0, stream>>>(
        out, x, gamma, beta, mu, rs);
}

// Round 3
// 287.823 us; speedup vs baseline: 4.5370x; 1.2177x over previous
//
#include <hip/hip_runtime.h>

#define N_NODES 100000
#define NPAD    100352          // 392*256, padded row count for A
#define DIM     128
#define K2      256             // concatenated K ([mean | x])
#define SCAN_B  1024
#define NSCANB  ((N_NODES + SCAN_B - 1) / SCAN_B)   // 98

typedef __attribute__((ext_vector_type(8))) short bf16x8;
typedef __attribute__((ext_vector_type(4))) float f32x4;

__device__ __forceinline__ void atomAddF(float* p, float v) { unsafeAtomicAdd(p, v); }

__device__ __forceinline__ float bf2f(unsigned short u) {
    union { unsigned u; float f; } c; c.u = ((unsigned)u) << 16; return c.f;
}
__device__ __forceinline__ unsigned short f2bf(float f) {
    union { float f; unsigned u; } c; c.f = f;
    unsigned r = (c.u + 0x7FFF + ((c.u >> 16) & 1)) >> 16;   // RNE
    return (unsigned short)r;
}
__device__ __forceinline__ unsigned packbf(float a, float b) {
    return (unsigned)f2bf(a) | ((unsigned)f2bf(b) << 16);
}

// ---------------------------------------------------------------------------
// CSR build
// ---------------------------------------------------------------------------
__global__ __launch_bounds__(256) void hist_kernel(
    const int* __restrict__ ei, int* __restrict__ counts, int E)
{
    int e = blockIdx.x * 256 + threadIdx.x;
    if (e >= E) return;
    atomicAdd(&counts[ei[E + e]], 1);
}

__global__ __launch_bounds__(SCAN_B) void scan_block_kernel(
    const int* __restrict__ counts, int* __restrict__ incl, int* __restrict__ blksum)
{
    __shared__ int sh[SCAN_B];
    int t = threadIdx.x;
    int i = blockIdx.x * SCAN_B + t;
    sh[t] = (i < N_NODES) ? counts[i] : 0;
    __syncthreads();
    #pragma unroll
    for (int ofs = 1; ofs < SCAN_B; ofs <<= 1) {
        int add = (t >= ofs) ? sh[t - ofs] : 0;
        __syncthreads();
        sh[t] += add;
        __syncthreads();
    }
    if (i < N_NODES) incl[i] = sh[t];
    if (t == SCAN_B - 1) blksum[blockIdx.x] = sh[t];
}

__global__ void scan_tops_kernel(const int* __restrict__ blksum, int* __restrict__ blkoff)
{
    if (threadIdx.x == 0) {
        int run = 0;
        for (int b = 0; b < NSCANB; ++b) { blkoff[b] = run; run += blksum[b]; }
    }
}

__global__ __launch_bounds__(256) void scan_add_kernel(
    const int* __restrict__ counts, const int* __restrict__ incl,
    const int* __restrict__ blkoff,
    int* __restrict__ row_start, int* __restrict__ wo, int E)
{
    int i = blockIdx.x * 256 + threadIdx.x;
    if (i == 0) row_start[N_NODES] = E;
    if (i >= N_NODES) return;
    int excl = incl[i] + blkoff[i / SCAN_B] - counts[i];
    row_start[i] = excl;
    wo[i] = excl;
}

__global__ __launch_bounds__(256) void fill_kernel(
    const int* __restrict__ ei, int* __restrict__ wo, int* __restrict__ srcs, int E)
{
    int e = blockIdx.x * 256 + threadIdx.x;
    if (e >= E) return;
    int dst = ei[E + e];
    int pos = atomicAdd(&wo[dst], 1);
    srcs[pos] = ei[e];
}

// ---------------------------------------------------------------------------
// x (fp32) -> bf16 into axk[n][128:256]
// ---------------------------------------------------------------------------
__global__ __launch_bounds__(256) void convert_x_kernel(
    const float* __restrict__ x, unsigned short* __restrict__ axk)
{
    int i = blockIdx.x * 256 + threadIdx.x;       // one thread per 8 floats
    if (i >= N_NODES * 16) return;
    int n = i >> 4, c8 = (i & 15) << 3;
    const float4* xp = reinterpret_cast<const float4*>(x + (size_t)n * DIM + c8);
    float4 v0 = xp[0], v1 = xp[1];
    uint4 o;
    o.x = packbf(v0.x, v0.y); o.y = packbf(v0.z, v0.w);
    o.z = packbf(v1.x, v1.y); o.w = packbf(v1.z, v1.w);
    *reinterpret_cast<uint4*>(axk + (size_t)n * K2 + DIM + c8) = o;
}

// ---------------------------------------------------------------------------
// Weights -> bf16 in MFMA B-fragment order:
// wb[((kk*8+dt)*64 + lane)*8 + j] = Wcat[dt*16+(lane&15)][kk*32+(lane>>4)*8+j]
// Wcat[d][k] = Wl[d][k] (k<128) else Wr[d][k-128]
// ---------------------------------------------------------------------------
__global__ __launch_bounds__(256) void wb_build_kernel(
    const float* __restrict__ Wl, const float* __restrict__ Wr,
    unsigned short* __restrict__ wb)
{
    int id = blockIdx.x * 256 + threadIdx.x;      // 4096 total
    int l = id & 63, dt = (id >> 6) & 7, kk = id >> 9;
    int d = dt * 16 + (l & 15);
    int k = kk * 32 + (l >> 4) * 8;
    const float* src = (k < DIM) ? (Wl + (size_t)d * DIM + k)
                                 : (Wr + (size_t)d * DIM + (k - DIM));
    uint4 o;
    o.x = packbf(src[0], src[1]); o.y = packbf(src[2], src[3]);
    o.z = packbf(src[4], src[5]); o.w = packbf(src[6], src[7]);
    *reinterpret_cast<uint4*>(wb + (size_t)id * 8) = o;
}

// ---------------------------------------------------------------------------
// Aggregation: 32 lanes per node, bf16 gather, fp32 accumulate, bf16 mean
// into axk[n][0:128]. No atomics.
// ---------------------------------------------------------------------------
__global__ __launch_bounds__(256) void aggregate_kernel(
    const int* __restrict__ srcs, const int* __restrict__ row_start,
    unsigned short* __restrict__ axk)
{
    int n = blockIdx.x * 8 + (threadIdx.x >> 5);
    if (n >= N_NODES) return;
    int lane = threadIdx.x & 31;
    int beg = row_start[n], end = row_start[n + 1];
    float a0 = 0.f, a1 = 0.f, a2 = 0.f, a3 = 0.f;
    int e = beg;
    for (; e + 1 < end; e += 2) {
        ushort4 v0 = *reinterpret_cast<const ushort4*>(axk + (size_t)srcs[e]     * K2 + DIM + lane * 4);
        ushort4 v1 = *reinterpret_cast<const ushort4*>(axk + (size_t)srcs[e + 1] * K2 + DIM + lane * 4);
        a0 += bf2f(v0.x) + bf2f(v1.x);
        a1 += bf2f(v0.y) + bf2f(v1.y);
        a2 += bf2f(v0.z) + bf2f(v1.z);
        a3 += bf2f(v0.w) + bf2f(v1.w);
    }
    if (e < end) {
        ushort4 v = *reinterpret_cast<const ushort4*>(axk + (size_t)srcs[e] * K2 + DIM + lane * 4);
        a0 += bf2f(v.x); a1 += bf2f(v.y); a2 += bf2f(v.z); a3 += bf2f(v.w);
    }
    float inv = 1.0f / (float)max(end - beg, 1);
    ushort4 o;
    o.x = f2bf(a0 * inv); o.y = f2bf(a1 * inv);
    o.z = f2bf(a2 * inv); o.w = f2bf(a3 * inv);
    *reinterpret_cast<ushort4*>(axk + (size_t)n * K2 + lane * 4) = o;
}

// ---------------------------------------------------------------------------
// MFMA GEMM: out[n][d] = sum_k axk[n][k] * Wcat[d][k] + bl[d]
// Block: 4 waves x 64 rows = 256 rows. Per wave: 4 row-tiles x 8 d-tiles,
// K=256 in 8 steps of 32 (v_mfma_f32_16x16x32_bf16).
// B staged in LDS in fragment order (conflict-free ds_read_b128).
// Fused per-channel sum/sumsq partials for BatchNorm.
// ---------------------------------------------------------------------------
__global__ __launch_bounds__(256) void mfma_gemm_kernel(
    const unsigned short* __restrict__ axk, const unsigned short* __restrict__ wb,
    const float* __restrict__ bl,
    float* __restrict__ out, float* __restrict__ ssum, float* __restrict__ ssq)
{
    __shared__ unsigned short Blds[32768];   // 64 KB, fragment-ordered
    __shared__ float sred[4][DIM];
    __shared__ float qred[4][DIM];

    const int t = threadIdx.x;
    {
        const uint4* g = reinterpret_cast<const uint4*>(wb);
        uint4* s = reinterpret_cast<uint4*>(Blds);
        #pragma unroll
        for (int j = 0; j < 16; ++j) s[t + j * 256] = g[t + j * 256];
    }
    __syncthreads();

    const int wave = t >> 6, lane = t & 63;
    const int rowbase = blockIdx.x * 256 + wave * 64;
    const int lrow = lane & 15, lk = lane >> 4;

    f32x4 acc[4][8];
    #pragma unroll
    for (int rt = 0; rt < 4; ++rt)
        #pragma unroll
        for (int dt = 0; dt < 8; ++dt)
            acc[rt][dt] = (f32x4){0.f, 0.f, 0.f, 0.f};

    const unsigned short* abase = axk + (size_t)rowbase * K2 + lk * 8;

    #pragma unroll
    for (int kk = 0; kk < 8; ++kk) {
        bf16x8 a[4];
        #pragma unroll
        for (int rt = 0; rt < 4; ++rt)
            a[rt] = *reinterpret_cast<const bf16x8*>(abase + (size_t)(rt * 16 + lrow) * K2 + kk * 32);
        #pragma unroll
        for (int dt = 0; dt < 8; ++dt) {
            bf16x8 b = *reinterpret_cast<const bf16x8*>(&Blds[((kk * 8 + dt) * 64 + lane) * 8]);
            #pragma unroll
            for (int rt = 0; rt < 4; ++rt)
                acc[rt][dt] = __builtin_amdgcn_mfma_f32_16x16x32_bf16(a[rt], b, acc[rt][dt], 0, 0, 0);
        }
    }

    // bias
    float blv[8];
    #pragma unroll
    for (int dt = 0; dt < 8; ++dt) blv[dt] = bl[dt * 16 + lrow];
    #pragma unroll
    for (int rt = 0; rt < 4; ++rt)
        #pragma unroll
        for (int dt = 0; dt < 8; ++dt)
            #pragma unroll
            for (int r = 0; r < 4; ++r) acc[rt][dt][r] += blv[dt];

    // store pre-BN activations (col = lrow, row = lk*4 + r within tile)
    #pragma unroll
    for (int rt = 0; rt < 4; ++rt)
        #pragma unroll
        for (int r = 0; r < 4; ++r) {
            int row = rowbase + rt * 16 + lk * 4 + r;
            if (row < N_NODES) {
                #pragma unroll
                for (int dt = 0; dt < 8; ++dt)
                    out[(size_t)row * DIM + dt * 16 + lrow] = acc[rt][dt][r];
            }
        }

    // BN partial stats: per channel d = dt*16 + lrow
    #pragma unroll
    for (int dt = 0; dt < 8; ++dt) {
        float s = 0.f, q = 0.f;
        #pragma unroll
        for (int rt = 0; rt < 4; ++rt)
            #pragma unroll
            for (int r = 0; r < 4; ++r) {
                int row = rowbase + rt * 16 + lk * 4 + r;
                if (row < N_NODES) { float v = acc[rt][dt][r]; s += v; q = fmaf(v, v, q); }
            }
        s += __shfl_xor(s, 16); q += __shfl_xor(q, 16);
        s += __shfl_xor(s, 32); q += __shfl_xor(q, 32);
        if (lane < 16) { sred[wave][dt * 16 + lane] = s; qred[wave][dt * 16 + lane] = q; }
    }
    __syncthreads();
    if (t < DIM) {
        float s = sred[0][t] + sred[1][t] + sred[2][t] + sred[3][t];
        float q = qred[0][t] + qred[1][t] + qred[2][t] + qred[3][t];
        atomAddF(&ssum[t], s);
        atomAddF(&ssq[t], q);
    }
}

// ---------------------------------------------------------------------------
__global__ void stats_kernel(const float* __restrict__ ssum, const float* __restrict__ ssq,
                             float* __restrict__ mu, float* __restrict__ rs)
{
    int d = threadIdx.x;
    float m = ssum[d] * (1.0f / N_NODES);
    float v = ssq[d] * (1.0f / N_NODES) - m * m;
    mu[d] = m;
    rs[d] = rsqrtf(fmaxf(v, 0.f) + 1e-5f);
}

// ---------------------------------------------------------------------------
__global__ __launch_bounds__(256) void epilogue_kernel(
    float* __restrict__ out, const float* __restrict__ x,
    const float* __restrict__ gamma, const float* __restrict__ beta,
    const float* __restrict__ mu, const float* __restrict__ rs)
{
    size_t i   = (size_t)blockIdx.x * 256 + threadIdx.x;
    size_t idx = i * 4;
    if (idx >= (size_t)N_NODES * DIM) return;
    int c = (int)(idx & (DIM - 1));
    float4 p  = *reinterpret_cast<const float4*>(out + idx);
    float4 xv = *reinterpret_cast<const float4*>(x + idx);
    float4 gv = *reinterpret_cast<const float4*>(gamma + c);
    float4 bv = *reinterpret_cast<const float4*>(beta + c);
    float4 mv = *reinterpret_cast<const float4*>(mu + c);
    float4 rv = *reinterpret_cast<const float4*>(rs + c);
    float4 o;
    o.x = fmaxf(fmaf(gv.x * (p.x - mv.x), rv.x, bv.x), 0.f) + xv.x;
    o.y = fmaxf(fmaf(gv.y * (p.y - mv.y), rv.y, bv.y), 0.f) + xv.y;
    o.z = fmaxf(fmaf(gv.z * (p.z - mv.z), rv.z, bv.z), 0.f) + xv.z;
    o.w = fmaxf(fmaf(gv.w * (p.w - mv.w), rv.w, bv.w), 0.f) + xv.w;
    *reinterpret_cast<float4*>(out + idx) = o;
}

// ---------------------------------------------------------------------------
extern "C" void kernel_launch(void* const* d_in, const int* in_sizes, int n_in,
                              void* d_out, int out_size, void* d_ws, size_t ws_size,
                              hipStream_t stream)
{
    const float* x     = (const float*)d_in[0];
    const int*   ei    = (const int*)  d_in[1];
    const float* Wl    = (const float*)d_in[2];
    const float* bl    = (const float*)d_in[3];
    const float* Wr    = (const float*)d_in[4];
    const float* gamma = (const float*)d_in[5];
    const float* beta  = (const float*)d_in[6];
    float* out = (float*)d_out;

    const int E = in_sizes[1] / 2;

    // ws layout:
    // axk[NPAD*256] bf16 | wb[32768] bf16 | srcs[E] i32 | row_start[N+1] |
    // wo[N] | incl[N] | blksum[128] | blkoff[128] |
    // counts[N] | ssum[D] | ssq[D] | mu[D] | rs[D]   (counts..ssq zeroed)
    char* w = (char*)d_ws;
    unsigned short* axk = (unsigned short*)w;      w += (size_t)NPAD * K2 * 2;
    unsigned short* wb  = (unsigned short*)w;      w += (size_t)32768 * 2;
    int*   srcs      = (int*)w;                    w += (size_t)E * 4;
    int*   row_start = (int*)w;                    w += (size_t)(N_NODES + 1) * 4;
    int*   wo        = (int*)w;                    w += (size_t)N_NODES * 4;
    int*   incl      = (int*)w;                    w += (size_t)N_NODES * 4;
    int*   blksum    = (int*)w;                    w += 128 * 4;
    int*   blkoff    = (int*)w;                    w += 128 * 4;
    int*   counts    = (int*)w;                    w += (size_t)N_NODES * 4;
    float* ssum      = (float*)w;                  w += DIM * 4;
    float* ssq       = (float*)w;                  w += DIM * 4;
    float* mu        = (float*)w;                  w += DIM * 4;
    float* rs        = (float*)w;                  /* end */

    hipMemsetAsync(counts, 0, ((size_t)N_NODES + 2 * DIM) * 4, stream);

    hist_kernel<<<(E + 255) / 256, 256, 0, stream>>>(ei, counts, E);
    scan_block_kernel<<<NSCANB, SCAN_B, 0, stream>>>(counts, incl, blksum);
    scan_tops_kernel<<<1, 64, 0, stream>>>(blksum, blkoff);
    scan_add_kernel<<<(N_NODES + 255) / 256, 256, 0, stream>>>(
        counts, incl, blkoff, row_start, wo, E);
    fill_kernel<<<(E + 255) / 256, 256, 0, stream>>>(ei, wo, srcs, E);

    convert_x_kernel<<<(N_NODES * 16 + 255) / 256, 256, 0, stream>>>(x, axk);
    wb_build_kernel<<<16, 256, 0, stream>>>(Wl, Wr, wb);

    aggregate_kernel<<<(N_NODES + 7) / 8, 256, 0, stream>>>(srcs, row_start, axk);

    mfma_gemm_kernel<<<(N_NODES + 255) / 256, 256, 0, stream>>>(
        axk, wb, bl, out, ssum, ssq);

    stats_kernel<<<1, DIM, 0, stream>>>(ssum, ssq, mu, rs);

    epilogue_kernel<<<((size_t)N_NODES * DIM / 4 + 255) / 256, 256, 0, stream>>>(
        out, x, gamma, beta, mu, rs);
}

// Round 4
// 263.758 us; speedup vs baseline: 4.9509x; 1.0912x over previous
//
#include <hip/hip_runtime.h>

#define N_NODES 100000
#define NPAD    100352          // padded row count for A
#define DIM     128
#define K2      256             // concatenated K ([mean | x])
#define SCAN_B  1024
#define NSCANB  ((N_NODES + SCAN_B - 1) / SCAN_B)   // 98
#define CONVB   6250            // convert blocks: N*16/256
#define WBB     16              // wb_build blocks
#define NSHARD  8
#define SHROWS  ((N_NODES + NSHARD - 1) / NSHARD)   // 12500
#define BPS     128             // fill blocks per shard

typedef __attribute__((ext_vector_type(8))) short bf16x8;
typedef __attribute__((ext_vector_type(4))) float f32x4;

__device__ __forceinline__ void atomAddF(float* p, float v) { unsafeAtomicAdd(p, v); }

__device__ __forceinline__ float bf2f(unsigned short u) {
    union { unsigned u; float f; } c; c.u = ((unsigned)u) << 16; return c.f;
}
__device__ __forceinline__ unsigned short f2bf(float f) {
    union { float f; unsigned u; } c; c.f = f;
    unsigned r = (c.u + 0x7FFF + ((c.u >> 16) & 1)) >> 16;   // RNE
    return (unsigned short)r;
}
__device__ __forceinline__ unsigned packbf(float a, float b) {
    return (unsigned)f2bf(a) | ((unsigned)f2bf(b) << 16);
}

// ---------------------------------------------------------------------------
// Phase 1 (merged): hist(dst) | x->bf16 into axk[:,128:256] | W->bf16 frag order
// ---------------------------------------------------------------------------
__global__ __launch_bounds__(256) void phase1_kernel(
    const float* __restrict__ x, const int* __restrict__ ei,
    const float* __restrict__ Wl, const float* __restrict__ Wr,
    unsigned short* __restrict__ axk, unsigned short* __restrict__ wb,
    int* __restrict__ counts, int E, int HB)
{
    int b = blockIdx.x;
    if (b < HB) {                              // ---- histogram of dst
        int e = b * 256 + threadIdx.x;
        if (e < E) atomicAdd(&counts[ei[E + e]], 1);
    } else if (b < HB + CONVB) {               // ---- x -> bf16
        int i = (b - HB) * 256 + threadIdx.x;  // one thread per 8 floats
        int n = i >> 4, c8 = (i & 15) << 3;
        const float4* xp = reinterpret_cast<const float4*>(x + (size_t)n * DIM + c8);
        float4 v0 = xp[0], v1 = xp[1];
        uint4 o;
        o.x = packbf(v0.x, v0.y); o.y = packbf(v0.z, v0.w);
        o.z = packbf(v1.x, v1.y); o.w = packbf(v1.z, v1.w);
        *reinterpret_cast<uint4*>(axk + (size_t)n * K2 + DIM + c8) = o;
    } else {                                   // ---- weights -> fragment order
        int id = (b - HB - CONVB) * 256 + threadIdx.x;   // 4096 total
        int l = id & 63, dt = (id >> 6) & 7, kk = id >> 9;
        int d = dt * 16 + (l & 15);
        int k = kk * 32 + (l >> 4) * 8;
        const float* src = (k < DIM) ? (Wl + (size_t)d * DIM + k)
                                     : (Wr + (size_t)d * DIM + (k - DIM));
        uint4 o;
        o.x = packbf(src[0], src[1]); o.y = packbf(src[2], src[3]);
        o.z = packbf(src[4], src[5]); o.w = packbf(src[6], src[7]);
        *reinterpret_cast<uint4*>(wb + (size_t)id * 8) = o;
    }
}

// ---------------------------------------------------------------------------
// CSR scan
// ---------------------------------------------------------------------------
__global__ __launch_bounds__(SCAN_B) void scan_block_kernel(
    const int* __restrict__ counts, int* __restrict__ incl, int* __restrict__ blksum)
{
    __shared__ int sh[SCAN_B];
    int t = threadIdx.x;
    int i = blockIdx.x * SCAN_B + t;
    sh[t] = (i < N_NODES) ? counts[i] : 0;
    __syncthreads();
    #pragma unroll
    for (int ofs = 1; ofs < SCAN_B; ofs <<= 1) {
        int add = (t >= ofs) ? sh[t - ofs] : 0;
        __syncthreads();
        sh[t] += add;
        __syncthreads();
    }
    if (i < N_NODES) incl[i] = sh[t];
    if (t == SCAN_B - 1) blksum[blockIdx.x] = sh[t];
}

__global__ __launch_bounds__(256) void scan_add_kernel(
    const int* __restrict__ counts, const int* __restrict__ incl,
    const int* __restrict__ blksum,
    int* __restrict__ row_start, int* __restrict__ wo, int E)
{
    __shared__ int soff;
    int b = blockIdx.x;
    if (threadIdx.x == 0) {
        int sb = (b * 256) >> 10;        // which scan-block this block lies in
        int run = 0;
        for (int j = 0; j < sb; ++j) run += blksum[j];
        soff = run;
    }
    __syncthreads();
    int i = b * 256 + threadIdx.x;
    if (i == 0) row_start[N_NODES] = E;
    if (i >= N_NODES) return;
    int excl = incl[i] + soff - counts[i];
    row_start[i] = excl;
    wo[i] = excl;
}

// ---------------------------------------------------------------------------
// XCD-sharded bucket fill: shard q (dst in [q*SHROWS,(q+1)*SHROWS)) handled
// only by blocks with blockIdx%8==q, so each shard's contiguous srcs window
// stays in one XCD's L2 (single writeback per line instead of ~8).
// ---------------------------------------------------------------------------
__global__ __launch_bounds__(256) void fill_kernel(
    const int* __restrict__ ei, int* __restrict__ wo, int* __restrict__ srcs, int E)
{
    int shard = blockIdx.x & (NSHARD - 1);
    int widx  = blockIdx.x >> 3;
    int lo = shard * SHROWS;
    int hi = min(lo + SHROWS, N_NODES);
    for (int e = widx * 256 + threadIdx.x; e < E; e += BPS * 256) {
        int dst = ei[E + e];
        int src = ei[e];
        if (dst >= lo && dst < hi) {
            int pos = atomicAdd(&wo[dst], 1);
            srcs[pos] = src;
        }
    }
}

// ---------------------------------------------------------------------------
// Aggregation: 32 lanes per node, bf16 gather, fp32 accumulate, bf16 mean
// into axk[n][0:128]. No atomics.
// ---------------------------------------------------------------------------
__global__ __launch_bounds__(256) void aggregate_kernel(
    const int* __restrict__ srcs, const int* __restrict__ row_start,
    unsigned short* __restrict__ axk)
{
    int n = blockIdx.x * 8 + (threadIdx.x >> 5);
    if (n >= N_NODES) return;
    int lane = threadIdx.x & 31;
    int beg = row_start[n], end = row_start[n + 1];
    float a0 = 0.f, a1 = 0.f, a2 = 0.f, a3 = 0.f;
    int e = beg;
    for (; e + 1 < end; e += 2) {
        ushort4 v0 = *reinterpret_cast<const ushort4*>(axk + (size_t)srcs[e]     * K2 + DIM + lane * 4);
        ushort4 v1 = *reinterpret_cast<const ushort4*>(axk + (size_t)srcs[e + 1] * K2 + DIM + lane * 4);
        a0 += bf2f(v0.x) + bf2f(v1.x);
        a1 += bf2f(v0.y) + bf2f(v1.y);
        a2 += bf2f(v0.z) + bf2f(v1.z);
        a3 += bf2f(v0.w) + bf2f(v1.w);
    }
    if (e < end) {
        ushort4 v = *reinterpret_cast<const ushort4*>(axk + (size_t)srcs[e] * K2 + DIM + lane * 4);
        a0 += bf2f(v.x); a1 += bf2f(v.y); a2 += bf2f(v.z); a3 += bf2f(v.w);
    }
    float inv = 1.0f / (float)max(end - beg, 1);
    ushort4 o;
    o.x = f2bf(a0 * inv); o.y = f2bf(a1 * inv);
    o.z = f2bf(a2 * inv); o.w = f2bf(a3 * inv);
    *reinterpret_cast<ushort4*>(axk + (size_t)n * K2 + lane * 4) = o;
}

// ---------------------------------------------------------------------------
// MFMA GEMM: out[n][d] = sum_k axk[n][k] * Wcat[d][k] + bl[d]
// 4 waves x 64 rows; per wave 4 row-tiles x 8 d-tiles; K=256 in 8 MFMA steps.
// Fused per-channel BN partials.
// ---------------------------------------------------------------------------
__global__ __launch_bounds__(256) void mfma_gemm_kernel(
    const unsigned short* __restrict__ axk, const unsigned short* __restrict__ wb,
    const float* __restrict__ bl,
    float* __restrict__ out, float* __restrict__ ssum, float* __restrict__ ssq)
{
    __shared__ unsigned short Blds[32768];   // 64 KB, fragment-ordered
    __shared__ float sred[4][DIM];
    __shared__ float qred[4][DIM];

    const int t = threadIdx.x;
    {
        const uint4* g = reinterpret_cast<const uint4*>(wb);
        uint4* s = reinterpret_cast<uint4*>(Blds);
        #pragma unroll
        for (int j = 0; j < 16; ++j) s[t + j * 256] = g[t + j * 256];
    }
    __syncthreads();

    const int wave = t >> 6, lane = t & 63;
    const int rowbase = blockIdx.x * 256 + wave * 64;
    const int lrow = lane & 15, lk = lane >> 4;

    f32x4 acc[4][8];
    #pragma unroll
    for (int rt = 0; rt < 4; ++rt)
        #pragma unroll
        for (int dt = 0; dt < 8; ++dt)
            acc[rt][dt] = (f32x4){0.f, 0.f, 0.f, 0.f};

    const unsigned short* abase = axk + (size_t)rowbase * K2 + lk * 8;

    #pragma unroll
    for (int kk = 0; kk < 8; ++kk) {
        bf16x8 a[4];
        #pragma unroll
        for (int rt = 0; rt < 4; ++rt)
            a[rt] = *reinterpret_cast<const bf16x8*>(abase + (size_t)(rt * 16 + lrow) * K2 + kk * 32);
        #pragma unroll
        for (int dt = 0; dt < 8; ++dt) {
            bf16x8 b = *reinterpret_cast<const bf16x8*>(&Blds[((kk * 8 + dt) * 64 + lane) * 8]);
            #pragma unroll
            for (int rt = 0; rt < 4; ++rt)
                acc[rt][dt] = __builtin_amdgcn_mfma_f32_16x16x32_bf16(a[rt], b, acc[rt][dt], 0, 0, 0);
        }
    }

    float blv[8];
    #pragma unroll
    for (int dt = 0; dt < 8; ++dt) blv[dt] = bl[dt * 16 + lrow];
    #pragma unroll
    for (int rt = 0; rt < 4; ++rt)
        #pragma unroll
        for (int dt = 0; dt < 8; ++dt)
            #pragma unroll
            for (int r = 0; r < 4; ++r) acc[rt][dt][r] += blv[dt];

    #pragma unroll
    for (int rt = 0; rt < 4; ++rt)
        #pragma unroll
        for (int r = 0; r < 4; ++r) {
            int row = rowbase + rt * 16 + lk * 4 + r;
            if (row < N_NODES) {
                #pragma unroll
                for (int dt = 0; dt < 8; ++dt)
                    out[(size_t)row * DIM + dt * 16 + lrow] = acc[rt][dt][r];
            }
        }

    #pragma unroll
    for (int dt = 0; dt < 8; ++dt) {
        float s = 0.f, q = 0.f;
        #pragma unroll
        for (int rt = 0; rt < 4; ++rt)
            #pragma unroll
            for (int r = 0; r < 4; ++r) {
                int row = rowbase + rt * 16 + lk * 4 + r;
                if (row < N_NODES) { float v = acc[rt][dt][r]; s += v; q = fmaf(v, v, q); }
            }
        s += __shfl_xor(s, 16); q += __shfl_xor(q, 16);
        s += __shfl_xor(s, 32); q += __shfl_xor(q, 32);
        if (lane < 16) { sred[wave][dt * 16 + lane] = s; qred[wave][dt * 16 + lane] = q; }
    }
    __syncthreads();
    if (t < DIM) {
        float s = sred[0][t] + sred[1][t] + sred[2][t] + sred[3][t];
        float q = qred[0][t] + qred[1][t] + qred[2][t] + qred[3][t];
        atomAddF(&ssum[t], s);
        atomAddF(&ssq[t], q);
    }
}

// ---------------------------------------------------------------------------
// Epilogue: BN (stats inlined from ssum/ssq) + ReLU + residual, in-place.
// ---------------------------------------------------------------------------
__global__ __launch_bounds__(256) void epilogue_kernel(
    float* __restrict__ out, const float* __restrict__ x,
    const float* __restrict__ gamma, const float* __restrict__ beta,
    const float* __restrict__ ssum, const float* __restrict__ ssq)
{
    size_t i   = (size_t)blockIdx.x * 256 + threadIdx.x;
    size_t idx = i * 4;
    if (idx >= (size_t)N_NODES * DIM) return;
    int c = (int)(idx & (DIM - 1));
    const float invN = 1.0f / (float)N_NODES;
    float4 sm = *reinterpret_cast<const float4*>(ssum + c);
    float4 sq = *reinterpret_cast<const float4*>(ssq + c);
    float4 mv, rv;
    mv.x = sm.x * invN; rv.x = rsqrtf(fmaxf(sq.x * invN - mv.x * mv.x, 0.f) + 1e-5f);
    mv.y = sm.y * invN; rv.y = rsqrtf(fmaxf(sq.y * invN - mv.y * mv.y, 0.f) + 1e-5f);
    mv.z = sm.z * invN; rv.z = rsqrtf(fmaxf(sq.z * invN - mv.z * mv.z, 0.f) + 1e-5f);
    mv.w = sm.w * invN; rv.w = rsqrtf(fmaxf(sq.w * invN - mv.w * mv.w, 0.f) + 1e-5f);
    float4 p  = *reinterpret_cast<const float4*>(out + idx);
    float4 xv = *reinterpret_cast<const float4*>(x + idx);
    float4 gv = *reinterpret_cast<const float4*>(gamma + c);
    float4 bv = *reinterpret_cast<const float4*>(beta + c);
    float4 o;
    o.x = fmaxf(fmaf(gv.x * (p.x - mv.x), rv.x, bv.x), 0.f) + xv.x;
    o.y = fmaxf(fmaf(gv.y * (p.y - mv.y), rv.y, bv.y), 0.f) + xv.y;
    o.z = fmaxf(fmaf(gv.z * (p.z - mv.z), rv.z, bv.z), 0.f) + xv.z;
    o.w = fmaxf(fmaf(gv.w * (p.w - mv.w), rv.w, bv.w), 0.f) + xv.w;
    *reinterpret_cast<float4*>(out + idx) = o;
}

// ---------------------------------------------------------------------------
extern "C" void kernel_launch(void* const* d_in, const int* in_sizes, int n_in,
                              void* d_out, int out_size, void* d_ws, size_t ws_size,
                              hipStream_t stream)
{
    const float* x     = (const float*)d_in[0];
    const int*   ei    = (const int*)  d_in[1];
    const float* Wl    = (const float*)d_in[2];
    const float* bl    = (const float*)d_in[3];
    const float* Wr    = (const float*)d_in[4];
    const float* gamma = (const float*)d_in[5];
    const float* beta  = (const float*)d_in[6];
    float* out = (float*)d_out;

    const int E  = in_sizes[1] / 2;
    const int HB = (E + 255) / 256;

    // ws layout:
    // axk[NPAD*256] bf16 | wb[32768] bf16 | srcs[E] i32 | row_start[N+1] |
    // wo[N] | incl[N] | blksum[128] | counts[N] | ssum[D] | ssq[D]
    char* w = (char*)d_ws;
    unsigned short* axk = (unsigned short*)w;      w += (size_t)NPAD * K2 * 2;
    unsigned short* wb  = (unsigned short*)w;      w += (size_t)32768 * 2;
    int*   srcs      = (int*)w;                    w += (size_t)E * 4;
    int*   row_start = (int*)w;                    w += (size_t)(N_NODES + 1) * 4;
    int*   wo        = (int*)w;                    w += (size_t)N_NODES * 4;
    int*   incl      = (int*)w;                    w += (size_t)N_NODES * 4;
    int*   blksum    = (int*)w;                    w += 128 * 4;
    int*   counts    = (int*)w;                    w += (size_t)N_NODES * 4;
    float* ssum      = (float*)w;                  w += DIM * 4;
    float* ssq       = (float*)w;                  /* end */

    // zero counts + ssum + ssq (contiguous)
    hipMemsetAsync(counts, 0, ((size_t)N_NODES + 2 * DIM) * 4, stream);

    phase1_kernel<<<HB + CONVB + WBB, 256, 0, stream>>>(
        x, ei, Wl, Wr, axk, wb, counts, E, HB);
    scan_block_kernel<<<NSCANB, SCAN_B, 0, stream>>>(counts, incl, blksum);
    scan_add_kernel<<<(N_NODES + 255) / 256, 256, 0, stream>>>(
        counts, incl, blksum, row_start, wo, E);
    fill_kernel<<<NSHARD * BPS, 256, 0, stream>>>(ei, wo, srcs, E);

    aggregate_kernel<<<(N_NODES + 7) / 8, 256, 0, stream>>>(srcs, row_start, axk);

    mfma_gemm_kernel<<<(N_NODES + 255) / 256, 256, 0, stream>>>(
        axk, wb, bl, out, ssum, ssq);

    epilogue_kernel<<<((size_t)N_NODES * DIM / 4 + 255) / 256, 256, 0, stream>>>(
        out, x, gamma, beta, ssum, ssq);
}

// Round 7
// 252.747 us; speedup vs baseline: 5.1666x; 1.0436x over previous
//
#include <hip/hip_runtime.h>

#define N_NODES 100000
#define NPAD    100352          // padded row count for A
#define DIM     128
#define K2      256             // concatenated K ([mean | x])
#define SCAN_B  1024
#define NSCANB  ((N_NODES + SCAN_B - 1) / SCAN_B)   // 98
#define CONVB   6250            // convert blocks: N*16/256
#define WBB     16              // wb_build blocks
#define NSHARD  8
#define SHROWS  ((N_NODES + NSHARD - 1) / NSHARD)   // 12500
#define BPS     128             // fill blocks per shard

typedef __attribute__((ext_vector_type(8))) short bf16x8;
typedef __attribute__((ext_vector_type(4))) float f32x4;

__device__ __forceinline__ void atomAddF(float* p, float v) { unsafeAtomicAdd(p, v); }

__device__ __forceinline__ float bf2f(unsigned short u) {
    union { unsigned u; float f; } c; c.u = ((unsigned)u) << 16; return c.f;
}
__device__ __forceinline__ unsigned short f2bf(float f) {
    union { float f; unsigned u; } c; c.f = f;
    unsigned r = (c.u + 0x7FFF + ((c.u >> 16) & 1)) >> 16;   // RNE
    return (unsigned short)r;
}
__device__ __forceinline__ unsigned packbf(float a, float b) {
    return (unsigned)f2bf(a) | ((unsigned)f2bf(b) << 16);
}

// ---------------------------------------------------------------------------
// Phase 1 (merged): hist(dst) | x->bf16 into axk[:,128:256] | W->bf16 frag order
// ---------------------------------------------------------------------------
__global__ __launch_bounds__(256) void phase1_kernel(
    const float* __restrict__ x, const int* __restrict__ ei,
    const float* __restrict__ Wl, const float* __restrict__ Wr,
    unsigned short* __restrict__ axk, unsigned short* __restrict__ wb,
    int* __restrict__ counts, int E, int HB)
{
    int b = blockIdx.x;
    if (b < HB) {                              // ---- histogram of dst
        int e = b * 256 + threadIdx.x;
        if (e < E) atomicAdd(&counts[ei[E + e]], 1);
    } else if (b < HB + CONVB) {               // ---- x -> bf16
        int i = (b - HB) * 256 + threadIdx.x;  // one thread per 8 floats
        int n = i >> 4, c8 = (i & 15) << 3;
        const float4* xp = reinterpret_cast<const float4*>(x + (size_t)n * DIM + c8);
        float4 v0 = xp[0], v1 = xp[1];
        uint4 o;
        o.x = packbf(v0.x, v0.y); o.y = packbf(v0.z, v0.w);
        o.z = packbf(v1.x, v1.y); o.w = packbf(v1.z, v1.w);
        *reinterpret_cast<uint4*>(axk + (size_t)n * K2 + DIM + c8) = o;
    } else {                                   // ---- weights -> fragment order
        int id = (b - HB - CONVB) * 256 + threadIdx.x;   // 4096 total
        int l = id & 63, dt = (id >> 6) & 7, kk = id >> 9;
        int d = dt * 16 + (l & 15);
        int k = kk * 32 + (l >> 4) * 8;
        const float* src = (k < DIM) ? (Wl + (size_t)d * DIM + k)
                                     : (Wr + (size_t)d * DIM + (k - DIM));
        uint4 o;
        o.x = packbf(src[0], src[1]); o.y = packbf(src[2], src[3]);
        o.z = packbf(src[4], src[5]); o.w = packbf(src[6], src[7]);
        *reinterpret_cast<uint4*>(wb + (size_t)id * 8) = o;
    }
}

// ---------------------------------------------------------------------------
// CSR scan
// ---------------------------------------------------------------------------
__global__ __launch_bounds__(SCAN_B) void scan_block_kernel(
    const int* __restrict__ counts, int* __restrict__ incl, int* __restrict__ blksum)
{
    __shared__ int sh[SCAN_B];
    int t = threadIdx.x;
    int i = blockIdx.x * SCAN_B + t;
    sh[t] = (i < N_NODES) ? counts[i] : 0;
    __syncthreads();
    #pragma unroll
    for (int ofs = 1; ofs < SCAN_B; ofs <<= 1) {
        int add = (t >= ofs) ? sh[t - ofs] : 0;
        __syncthreads();
        sh[t] += add;
        __syncthreads();
    }
    if (i < N_NODES) incl[i] = sh[t];
    if (t == SCAN_B - 1) blksum[blockIdx.x] = sh[t];
}

__global__ __launch_bounds__(256) void scan_add_kernel(
    const int* __restrict__ counts, const int* __restrict__ incl,
    const int* __restrict__ blksum,
    int* __restrict__ row_start, int* __restrict__ wo, int E)
{
    __shared__ int soff;
    int b = blockIdx.x;
    if (threadIdx.x == 0) {
        int sb = (b * 256) >> 10;
        int run = 0;
        for (int j = 0; j < sb; ++j) run += blksum[j];
        soff = run;
    }
    __syncthreads();
    int i = b * 256 + threadIdx.x;
    if (i == 0) row_start[N_NODES] = E;
    if (i >= N_NODES) return;
    int excl = incl[i] + soff - counts[i];
    row_start[i] = excl;
    wo[i] = excl;
}

// ---------------------------------------------------------------------------
// XCD-sharded bucket fill (one XCD owns each shard's contiguous srcs window)
// ---------------------------------------------------------------------------
__global__ __launch_bounds__(256) void fill_kernel(
    const int* __restrict__ ei, int* __restrict__ wo, int* __restrict__ srcs, int E)
{
    int shard = blockIdx.x & (NSHARD - 1);
    int widx  = blockIdx.x >> 3;
    int lo = shard * SHROWS;
    int hi = min(lo + SHROWS, N_NODES);
    for (int e = widx * 256 + threadIdx.x; e < E; e += BPS * 256) {
        int dst = ei[E + e];
        int src = ei[e];
        if (dst >= lo && dst < hi) {
            int pos = atomicAdd(&wo[dst], 1);
            srcs[pos] = src;
        }
    }
}

// ---------------------------------------------------------------------------
// Aggregation: 32 lanes per node, 4-deep unrolled bf16 gather, fp32 accum,
// bf16 mean into axk[n][0:128]. No atomics.
// ---------------------------------------------------------------------------
__global__ __launch_bounds__(256) void aggregate_kernel(
    const int* __restrict__ srcs, const int* __restrict__ row_start,
    unsigned short* __restrict__ axk)
{
    int n = blockIdx.x * 8 + (threadIdx.x >> 5);
    if (n >= N_NODES) return;
    int lane = threadIdx.x & 31;
    int beg = row_start[n], end = row_start[n + 1];
    float a0 = 0.f, a1 = 0.f, a2 = 0.f, a3 = 0.f;
    const unsigned short* xb = axk + DIM + lane * 4;
    int e = beg;
    for (; e + 3 < end; e += 4) {                  // 4 gathers in flight
        int s0 = srcs[e], s1 = srcs[e + 1], s2 = srcs[e + 2], s3 = srcs[e + 3];
        ushort4 v0 = *reinterpret_cast<const ushort4*>(xb + (size_t)s0 * K2);
        ushort4 v1 = *reinterpret_cast<const ushort4*>(xb + (size_t)s1 * K2);
        ushort4 v2 = *reinterpret_cast<const ushort4*>(xb + (size_t)s2 * K2);
        ushort4 v3 = *reinterpret_cast<const ushort4*>(xb + (size_t)s3 * K2);
        a0 += (bf2f(v0.x) + bf2f(v1.x)) + (bf2f(v2.x) + bf2f(v3.x));
        a1 += (bf2f(v0.y) + bf2f(v1.y)) + (bf2f(v2.y) + bf2f(v3.y));
        a2 += (bf2f(v0.z) + bf2f(v1.z)) + (bf2f(v2.z) + bf2f(v3.z));
        a3 += (bf2f(v0.w) + bf2f(v1.w)) + (bf2f(v2.w) + bf2f(v3.w));
    }
    for (; e < end; ++e) {
        ushort4 v = *reinterpret_cast<const ushort4*>(xb + (size_t)srcs[e] * K2);
        a0 += bf2f(v.x); a1 += bf2f(v.y); a2 += bf2f(v.z); a3 += bf2f(v.w);
    }
    float inv = 1.0f / (float)max(end - beg, 1);
    ushort4 o;
    o.x = f2bf(a0 * inv); o.y = f2bf(a1 * inv);
    o.z = f2bf(a2 * inv); o.w = f2bf(a3 * inv);
    *reinterpret_cast<ushort4*>(axk + (size_t)n * K2 + lane * 4) = o;
}

// ---------------------------------------------------------------------------
// MFMA GEMM: preBN[n][d] = sum_k axk[n][k] * Wcat[d][k] + bl[d]
// 4 waves x 64 rows; per wave 4 row-tiles x 8 d-tiles; K=256 in 8 MFMA steps.
// Pre-BN result stored as bf16 OVER the mean half of axk (rows owned by this
// wave were fully consumed by its k-loop -> race-free). Fused BN partials.
// ---------------------------------------------------------------------------
__global__ __launch_bounds__(256) void mfma_gemm_kernel(
    unsigned short* __restrict__ axk, const unsigned short* __restrict__ wb,
    const float* __restrict__ bl,
    float* __restrict__ ssum, float* __restrict__ ssq)
{
    __shared__ unsigned short Blds[32768];   // 64 KB, fragment-ordered
    __shared__ float sred[4][DIM];
    __shared__ float qred[4][DIM];

    const int t = threadIdx.x;
    {
        const uint4* g = reinterpret_cast<const uint4*>(wb);
        uint4* s = reinterpret_cast<uint4*>(Blds);
        #pragma unroll
        for (int j = 0; j < 16; ++j) s[t + j * 256] = g[t + j * 256];
    }
    __syncthreads();

    const int wave = t >> 6, lane = t & 63;
    const int rowbase = blockIdx.x * 256 + wave * 64;
    const int lrow = lane & 15, lk = lane >> 4;

    f32x4 acc[4][8];
    #pragma unroll
    for (int rt = 0; rt < 4; ++rt)
        #pragma unroll
        for (int dt = 0; dt < 8; ++dt)
            acc[rt][dt] = (f32x4){0.f, 0.f, 0.f, 0.f};

    const unsigned short* abase = axk + (size_t)rowbase * K2 + lk * 8;

    #pragma unroll
    for (int kk = 0; kk < 8; ++kk) {
        bf16x8 a[4];
        #pragma unroll
        for (int rt = 0; rt < 4; ++rt)
            a[rt] = *reinterpret_cast<const bf16x8*>(abase + (size_t)(rt * 16 + lrow) * K2 + kk * 32);
        #pragma unroll
        for (int dt = 0; dt < 8; ++dt) {
            bf16x8 b = *reinterpret_cast<const bf16x8*>(&Blds[((kk * 8 + dt) * 64 + lane) * 8]);
            #pragma unroll
            for (int rt = 0; rt < 4; ++rt)
                acc[rt][dt] = __builtin_amdgcn_mfma_f32_16x16x32_bf16(a[rt], b, acc[rt][dt], 0, 0, 0);
        }
    }

    // bias (part of BN input)
    #pragma unroll
    for (int dt = 0; dt < 8; ++dt) {
        float blv = bl[dt * 16 + lrow];
        #pragma unroll
        for (int rt = 0; rt < 4; ++rt)
            #pragma unroll
            for (int r = 0; r < 4; ++r) acc[rt][dt][r] += blv;
    }

    // store pre-BN as bf16 into the (consumed) mean half of axk
    #pragma unroll
    for (int rt = 0; rt < 4; ++rt)
        #pragma unroll
        for (int r = 0; r < 4; ++r) {
            int row = rowbase + rt * 16 + lk * 4 + r;
            if (row < N_NODES) {
                #pragma unroll
                for (int dt = 0; dt < 8; ++dt)
                    axk[(size_t)row * K2 + dt * 16 + lrow] = f2bf(acc[rt][dt][r]);
            }
        }

    // BN partial stats (fp32 accumulators, exact)
    #pragma unroll
    for (int dt = 0; dt < 8; ++dt) {
        float s = 0.f, q = 0.f;
        #pragma unroll
        for (int rt = 0; rt < 4; ++rt)
            #pragma unroll
            for (int r = 0; r < 4; ++r) {
                int row = rowbase + rt * 16 + lk * 4 + r;
                if (row < N_NODES) { float v = acc[rt][dt][r]; s += v; q = fmaf(v, v, q); }
            }
        s += __shfl_xor(s, 16); q += __shfl_xor(q, 16);
        s += __shfl_xor(s, 32); q += __shfl_xor(q, 32);
        if (lane < 16) { sred[wave][dt * 16 + lane] = s; qred[wave][dt * 16 + lane] = q; }
    }
    __syncthreads();
    if (t < DIM) {
        float s = sred[0][t] + sred[1][t] + sred[2][t] + sred[3][t];
        float q = qred[0][t] + qred[1][t] + qred[2][t] + qred[3][t];
        atomAddF(&ssum[t], s);
        atomAddF(&ssq[t], q);
    }
}

// ---------------------------------------------------------------------------
// Epilogue: BN (stats inlined) + ReLU + residual(bf16 x) -> fp32 out.
// One thread per 8 channels; reads one 512B axk row slice (preact+xb).
// ---------------------------------------------------------------------------
__global__ __launch_bounds__(256) void epilogue_kernel(
    const unsigned short* __restrict__ axk,
    const float* __restrict__ gamma, const float* __restrict__ beta,
    const float* __restrict__ ssum, const float* __restrict__ ssq,
    float* __restrict__ out)
{
    int i = blockIdx.x * 256 + threadIdx.x;   // one thread per 8 channels
    if (i >= N_NODES * 16) return;
    int n = i >> 4, c8 = (i & 15) << 3;
    const float invN = 1.0f / (float)N_NODES;

    ushort4 p0 = *reinterpret_cast<const ushort4*>(axk + (size_t)n * K2 + c8);
    ushort4 p1 = *reinterpret_cast<const ushort4*>(axk + (size_t)n * K2 + c8 + 4);
    ushort4 x0 = *reinterpret_cast<const ushort4*>(axk + (size_t)n * K2 + DIM + c8);
    ushort4 x1 = *reinterpret_cast<const ushort4*>(axk + (size_t)n * K2 + DIM + c8 + 4);

    float o[8];
    unsigned short pv[8] = {p0.x, p0.y, p0.z, p0.w, p1.x, p1.y, p1.z, p1.w};
    unsigned short xv[8] = {x0.x, x0.y, x0.z, x0.w, x1.x, x1.y, x1.z, x1.w};
    #pragma unroll
    for (int j = 0; j < 8; ++j) {
        int d = c8 + j;
        float m = ssum[d] * invN;
        float r = rsqrtf(fmaxf(ssq[d] * invN - m * m, 0.f) + 1e-5f);
        o[j] = fmaxf(gamma[d] * (bf2f(pv[j]) - m) * r + beta[d], 0.f) + bf2f(xv[j]);
    }
    float4 q0 = make_float4(o[0], o[1], o[2], o[3]);
    float4 q1 = make_float4(o[4], o[5], o[6], o[7]);
    *reinterpret_cast<float4*>(out + (size_t)n * DIM + c8) = q0;
    *reinterpret_cast<float4*>(out + (size_t)n * DIM + c8 + 4) = q1;
}

// ---------------------------------------------------------------------------
extern "C" void kernel_launch(void* const* d_in, const int* in_sizes, int n_in,
                              void* d_out, int out_size, void* d_ws, size_t ws_size,
                              hipStream_t stream)
{
    const float* x     = (const float*)d_in[0];
    const int*   ei    = (const int*)  d_in[1];
    const float* Wl    = (const float*)d_in[2];
    const float* bl    = (const float*)d_in[3];
    const float* Wr    = (const float*)d_in[4];
    const float* gamma = (const float*)d_in[5];
    const float* beta  = (const float*)d_in[6];
    float* out = (float*)d_out;

    const int E  = in_sizes[1] / 2;
    const int HB = (E + 255) / 256;

    // ws layout:
    // axk[NPAD*256] bf16 | wb[32768] bf16 | srcs[E] i32 | row_start[N+1] |
    // wo[N] | incl[N] | blksum[128] | counts[N] | ssum[D] | ssq[D]
    char* w = (char*)d_ws;
    unsigned short* axk = (unsigned short*)w;      w += (size_t)NPAD * K2 * 2;
    unsigned short* wb  = (unsigned short*)w;      w += (size_t)32768 * 2;
    int*   srcs      = (int*)w;                    w += (size_t)E * 4;
    int*   row_start = (int*)w;                    w += (size_t)(N_NODES + 1) * 4;
    int*   wo        = (int*)w;                    w += (size_t)N_NODES * 4;
    int*   incl      = (int*)w;                    w += (size_t)N_NODES * 4;
    int*   blksum    = (int*)w;                    w += 128 * 4;
    int*   counts    = (int*)w;                    w += (size_t)N_NODES * 4;
    float* ssum      = (float*)w;                  w += DIM * 4;
    float* ssq       = (float*)w;                  /* end */

    // zero counts + ssum + ssq (contiguous)
    hipMemsetAsync(counts, 0, ((size_t)N_NODES + 2 * DIM) * 4, stream);

    phase1_kernel<<<HB + CONVB + WBB, 256, 0, stream>>>(
        x, ei, Wl, Wr, axk, wb, counts, E, HB);
    scan_block_kernel<<<NSCANB, SCAN_B, 0, stream>>>(counts, incl, blksum);
    scan_add_kernel<<<(N_NODES + 255) / 256, 256, 0, stream>>>(
        counts, incl, blksum, row_start, wo, E);
    fill_kernel<<<NSHARD * BPS, 256, 0, stream>>>(ei, wo, srcs, E);

    aggregate_kernel<<<(N_NODES + 7) / 8, 256, 0, stream>>>(srcs, row_start, axk);

    mfma_gemm_kernel<<<(N_NODES + 255) / 256, 256, 0, stream>>>(
        axk, wb, bl, ssum, ssq);

    epilogue_kernel<<<(N_NODES * 16 + 255) / 256, 256, 0, stream>>>(
        axk, gamma, beta, ssum, ssq, out);
}